// Round 13
// baseline (3118.056 us; speedup 1.0000x reference)
//
#include <hip/hip_runtime.h>
#include <hip/hip_bf16.h>
#include <math.h>

#define BB 4
#define TT 4096
#define CC 1024
#define HH 16
#define NN 64
#define BT (BB*TT)            // 16384 rows
#define EPS_GN 6.4e-4f        // 1e-5 * 8^2
#define TMAX (TT-1)
#define LCH 64                // chunk length
#define CB 8                  // chunks per batch
#define NB 8                  // batches  (LCH*CB*NB == TT)
#define STR 68                // padded LDS row stride (multiple of 4 -> b128)

typedef __attribute__((ext_vector_type(8))) short bf16x8;
typedef __attribute__((ext_vector_type(4))) float f32x4;

__device__ __forceinline__ float sigmoidf_(float x) {
    return 1.0f / (1.0f + expf(-x));
}

__device__ __forceinline__ float waveReduceSum(float v) {
    #pragma unroll
    for (int off = 32; off > 0; off >>= 1)
        v += __shfl_xor(v, off, 64);
    return v;
}

__device__ __forceinline__ unsigned short f2bf(float f) {
    unsigned u = __float_as_uint(f);
    u += 0x7FFFu + ((u >> 16) & 1u);
    return (unsigned short)(u >> 16);
}
__device__ __forceinline__ float bf2f(unsigned short h) {
    return __uint_as_float(((unsigned)h) << 16);
}

__device__ __forceinline__ void gll16(const unsigned short* g, unsigned short* l) {
    __builtin_amdgcn_global_load_lds(
        (__attribute__((address_space(1))) void*)(g),
        (__attribute__((address_space(3))) void*)(l), 16, 0, 0);
}

// acc[r][c] += sum_k A(tr+r,k)*B(tc+c,k); element A(i,k)=A[i*SA0+k*SA1].
template<int SA0,int SA1,int SB0,int SB1>
__device__ __forceinline__ void gemm64(const float* __restrict__ A,
                                       const float* __restrict__ B,
                                       float acc[4][4], int tr, int tc) {
    #pragma unroll 2
    for (int kx = 0; kx < 64; kx += 4) {
        float a_[4][4];   // [r][kk]
        if (SA0 == 1) {
            #pragma unroll
            for (int kk = 0; kk < 4; kk++) {
                float4 t = *(const float4*)&A[tr + (kx + kk) * SA1];
                a_[0][kk] = t.x; a_[1][kk] = t.y; a_[2][kk] = t.z; a_[3][kk] = t.w;
            }
        } else {
            #pragma unroll
            for (int r = 0; r < 4; r++) {
                float4 t = *(const float4*)&A[(tr + r) * SA0 + kx];
                a_[r][0] = t.x; a_[r][1] = t.y; a_[r][2] = t.z; a_[r][3] = t.w;
            }
        }
        float b_[4][4];   // [cq][kk]
        if (SB0 == 1) {
            #pragma unroll
            for (int kk = 0; kk < 4; kk++) {
                float4 t = *(const float4*)&B[tc + (kx + kk) * SB1];
                b_[0][kk] = t.x; b_[1][kk] = t.y; b_[2][kk] = t.z; b_[3][kk] = t.w;
            }
        } else {
            #pragma unroll
            for (int cq = 0; cq < 4; cq++) {
                float4 t = *(const float4*)&B[(tc + cq) * SB0 + kx];
                b_[cq][0] = t.x; b_[cq][1] = t.y; b_[cq][2] = t.z; b_[cq][3] = t.w;
            }
        }
        #pragma unroll
        for (int r = 0; r < 4; r++)
            #pragma unroll
            for (int cq = 0; cq < 4; cq++)
                #pragma unroll
                for (int kk = 0; kk < 4; kk++)
                    acc[r][cq] = fmaf(a_[r][kk], b_[cq][kk], acc[r][cq]);
    }
}

// ---------------------------------------------------------------------------
// Split-conversion: fp32 (rows x CC, k-contig) -> bf16 hi + bf16 lo residual.
// ---------------------------------------------------------------------------
template<bool DOMIX>
__global__ __launch_bounds__(256) void conv_split(
    const float* __restrict__ X, const float* __restrict__ mix,
    unsigned short* __restrict__ Hi, unsigned short* __restrict__ Lo,
    int ngroups)
{
    int g = blockIdx.x * 256 + threadIdx.x;
    if (g >= ngroups) return;
    int m = g >> 7;                 // CC/8 = 128 groups per row
    int k = (g & 127) * 8;
    const float* px = X + (size_t)m * CC + k;
    float a[8];
    {
        float4 x0 = *(const float4*)px;
        float4 x1 = *(const float4*)(px + 4);
        a[0]=x0.x; a[1]=x0.y; a[2]=x0.z; a[3]=x0.w;
        a[4]=x1.x; a[5]=x1.y; a[6]=x1.z; a[7]=x1.w;
    }
    if (DOMIX) {
        float4 p0, p1;
        if ((m & (TT - 1)) == 0) {
            p0 = make_float4(0.f,0.f,0.f,0.f); p1 = p0;
        } else {
            p0 = *(const float4*)(px - CC);
            p1 = *(const float4*)(px - CC + 4);
        }
        float4 m0 = *(const float4*)(mix + k);
        float4 m1 = *(const float4*)(mix + k + 4);
        float pv[8] = {p0.x,p0.y,p0.z,p0.w,p1.x,p1.y,p1.z,p1.w};
        float mv[8] = {m0.x,m0.y,m0.z,m0.w,m1.x,m1.y,m1.z,m1.w};
        #pragma unroll
        for (int j = 0; j < 8; j++) a[j] += (pv[j] - a[j]) * mv[j];
    }
    unsigned short hi[8], lo[8];
    #pragma unroll
    for (int j = 0; j < 8; j++) {
        hi[j] = f2bf(a[j]);
        lo[j] = f2bf(a[j] - bf2f(hi[j]));
    }
    uint4 H, L;
    H.x = (unsigned)hi[0] | ((unsigned)hi[1] << 16);
    H.y = (unsigned)hi[2] | ((unsigned)hi[3] << 16);
    H.z = (unsigned)hi[4] | ((unsigned)hi[5] << 16);
    H.w = (unsigned)hi[6] | ((unsigned)hi[7] << 16);
    L.x = (unsigned)lo[0] | ((unsigned)lo[1] << 16);
    L.y = (unsigned)lo[2] | ((unsigned)lo[3] << 16);
    L.z = (unsigned)lo[4] | ((unsigned)lo[5] << 16);
    L.w = (unsigned)lo[6] | ((unsigned)lo[7] << 16);
    *(uint4*)(Hi + (size_t)g * 8) = H;
    *(uint4*)(Lo + (size_t)g * 8) = L;
}

// ---------------------------------------------------------------------------
// Fused mix+split for xr, xk, xv: reads x (+prev) ONCE, emits 3 hi/lo pairs.
// ---------------------------------------------------------------------------
__global__ __launch_bounds__(256) void conv_split_x3(
    const float* __restrict__ X,
    const float* __restrict__ mr, const float* __restrict__ mk,
    const float* __restrict__ mv,
    unsigned short* __restrict__ rH, unsigned short* __restrict__ rL,
    unsigned short* __restrict__ kH, unsigned short* __restrict__ kL,
    unsigned short* __restrict__ vH, unsigned short* __restrict__ vL)
{
    int g = blockIdx.x * 256 + threadIdx.x;
    int m = g >> 7;
    int k = (g & 127) * 8;
    const float* px = X + (size_t)m * CC + k;
    float xv8[8], pv[8];
    {
        float4 x0 = *(const float4*)px;
        float4 x1 = *(const float4*)(px + 4);
        xv8[0]=x0.x; xv8[1]=x0.y; xv8[2]=x0.z; xv8[3]=x0.w;
        xv8[4]=x1.x; xv8[5]=x1.y; xv8[6]=x1.z; xv8[7]=x1.w;
    }
    if ((m & (TT - 1)) == 0) {
        #pragma unroll
        for (int j = 0; j < 8; j++) pv[j] = 0.f;
    } else {
        float4 p0 = *(const float4*)(px - CC);
        float4 p1 = *(const float4*)(px - CC + 4);
        pv[0]=p0.x; pv[1]=p0.y; pv[2]=p0.z; pv[3]=p0.w;
        pv[4]=p1.x; pv[5]=p1.y; pv[6]=p1.z; pv[7]=p1.w;
    }
    const float* mixes[3] = {mr, mk, mv};
    unsigned short* His[3] = {rH, kH, vH};
    unsigned short* Los[3] = {rL, kL, vL};
    #pragma unroll
    for (int s = 0; s < 3; s++) {
        float4 m0 = *(const float4*)(mixes[s] + k);
        float4 m1 = *(const float4*)(mixes[s] + k + 4);
        float mv8[8] = {m0.x,m0.y,m0.z,m0.w,m1.x,m1.y,m1.z,m1.w};
        unsigned short hi[8], lo[8];
        #pragma unroll
        for (int j = 0; j < 8; j++) {
            float a = xv8[j] + (pv[j] - xv8[j]) * mv8[j];
            hi[j] = f2bf(a);
            lo[j] = f2bf(a - bf2f(hi[j]));
        }
        uint4 H, L;
        H.x = (unsigned)hi[0] | ((unsigned)hi[1] << 16);
        H.y = (unsigned)hi[2] | ((unsigned)hi[3] << 16);
        H.z = (unsigned)hi[4] | ((unsigned)hi[5] << 16);
        H.w = (unsigned)hi[6] | ((unsigned)hi[7] << 16);
        L.x = (unsigned)lo[0] | ((unsigned)lo[1] << 16);
        L.y = (unsigned)lo[2] | ((unsigned)lo[3] << 16);
        L.z = (unsigned)lo[4] | ((unsigned)lo[5] << 16);
        L.w = (unsigned)lo[6] | ((unsigned)lo[7] << 16);
        *(uint4*)(His[s] + (size_t)g * 8) = H;
        *(uint4*)(Los[s] + (size_t)g * 8) = L;
    }
}

// ---------------------------------------------------------------------------
// Stage-2 weight transpose+split: W (K,CC) n-contig -> (CC,Kp) k-contig hi/lo
// ---------------------------------------------------------------------------
__global__ __launch_bounds__(256) void conv_w2(
    const float* __restrict__ W, int K, int Kp,
    unsigned short* __restrict__ Hi, unsigned short* __restrict__ Lo)
{
    int idx = blockIdx.x * 256 + threadIdx.x;
    int nk8 = Kp >> 3;
    if (idx >= CC * nk8) return;
    int n = idx / nk8, k0 = (idx - n * nk8) * 8;
    unsigned short h8[8], l8[8];
    #pragma unroll
    for (int j = 0; j < 8; j++) {
        int k = k0 + j;
        float v = (k < K) ? W[(size_t)k * CC + n] : 0.f;
        h8[j] = f2bf(v);
        l8[j] = f2bf(v - bf2f(h8[j]));
    }
    uint4 H, L;
    H.x = (unsigned)h8[0] | ((unsigned)h8[1] << 16);
    H.y = (unsigned)h8[2] | ((unsigned)h8[3] << 16);
    H.z = (unsigned)h8[4] | ((unsigned)h8[5] << 16);
    H.w = (unsigned)h8[6] | ((unsigned)h8[7] << 16);
    L.x = (unsigned)l8[0] | ((unsigned)l8[1] << 16);
    L.y = (unsigned)l8[2] | ((unsigned)l8[3] << 16);
    L.z = (unsigned)l8[4] | ((unsigned)l8[5] << 16);
    L.w = (unsigned)l8[6] | ((unsigned)l8[7] << 16);
    *(uint4*)(Hi + (size_t)n * Kp + k0) = H;
    *(uint4*)(Lo + (size_t)n * Kp + k0) = L;
}

// ---------------------------------------------------------------------------
// Split-bf16 MFMA GEMM for big projections (unchanged — passed)
// ---------------------------------------------------------------------------
__global__ __launch_bounds__(256, 2) void gemm_split_bf16(
    const unsigned short* __restrict__ Ah, const unsigned short* __restrict__ Al,
    const unsigned short* __restrict__ Bh, const unsigned short* __restrict__ Bl,
    float* __restrict__ Out)
{
    __shared__ __align__(16) unsigned short lds[4][128 * 64];  // Ah,Al,Bh,Bl
    const int tid = threadIdx.x;
    const int lane = tid & 63;
    const int wave = tid >> 6;
    const int wm = (wave >> 1) * 64, wn = (wave & 1) * 64;
    const int wg = blockIdx.x;
    const int xcd = wg & 7;
    const int j = wg >> 3;
    const int m0 = ((j >> 3) * 8 + xcd) * 128;
    const int n0 = (j & 7) * 128;

    f32x4 acc[4][4];
    #pragma unroll
    for (int i = 0; i < 4; i++)
        #pragma unroll
        for (int jj = 0; jj < 4; jj++)
            acc[i][jj] = (f32x4){0.f, 0.f, 0.f, 0.f};

    for (int k0 = 0; k0 < CC; k0 += 64) {
        #pragma unroll
        for (int p = 0; p < 4; p++) {
            const unsigned short* sbase = (p == 0) ? Ah : (p == 1) ? Al
                                        : (p == 2) ? Bh : Bl;
            const int rbase = (p < 2) ? m0 : n0;
            #pragma unroll
            for (int i = 0; i < 4; i++) {
                int slot = i * 256 + wave * 64 + lane;
                int row = slot >> 3, gsl = slot & 7;
                const unsigned short* src = sbase
                    + (size_t)(rbase + row) * CC + k0 + ((gsl ^ (row & 7)) * 8);
                gll16(src, &lds[p][(size_t)(i * 256 + wave * 64) * 8]);
            }
        }
        __syncthreads();

        #pragma unroll
        for (int ks = 0; ks < 2; ks++) {
            bf16x8 bhf[4], blf[4];
            #pragma unroll
            for (int nt = 0; nt < 4; nt++) {
                int col = wn + nt * 16 + (lane & 15);
                int gk = ks * 4 + (lane >> 4);
                int el = col * 64 + ((gk ^ (col & 7)) * 8);
                bhf[nt] = *(const bf16x8*)&lds[2][el];
                blf[nt] = *(const bf16x8*)&lds[3][el];
            }
            #pragma unroll
            for (int mt = 0; mt < 4; mt++) {
                int row = wm + mt * 16 + (lane & 15);
                int gk = ks * 4 + (lane >> 4);
                int el = row * 64 + ((gk ^ (row & 7)) * 8);
                bf16x8 ahf = *(const bf16x8*)&lds[0][el];
                bf16x8 alf = *(const bf16x8*)&lds[1][el];
                #pragma unroll
                for (int nt = 0; nt < 4; nt++) {
                    acc[mt][nt] = __builtin_amdgcn_mfma_f32_16x16x32_bf16(
                        ahf, bhf[nt], acc[mt][nt], 0, 0, 0);
                    acc[mt][nt] = __builtin_amdgcn_mfma_f32_16x16x32_bf16(
                        alf, bhf[nt], acc[mt][nt], 0, 0, 0);
                    acc[mt][nt] = __builtin_amdgcn_mfma_f32_16x16x32_bf16(
                        ahf, blf[nt], acc[mt][nt], 0, 0, 0);
                }
            }
        }
        __syncthreads();
    }
    float* cf = (float*)&lds[0][0];    // 64*132*4 = 33.8 KB
    #pragma unroll
    for (int pass = 0; pass < 2; ++pass) {
        __syncthreads();
        if ((wave >> 1) == pass) {
            #pragma unroll
            for (int mt = 0; mt < 4; mt++)
                #pragma unroll
                for (int nt = 0; nt < 4; nt++)
                    #pragma unroll
                    for (int r = 0; r < 4; r++) {
                        int row = mt * 16 + (lane >> 4) * 4 + r;
                        int col = wn + nt * 16 + (lane & 15);
                        cf[row * 132 + col] = acc[mt][nt][r];
                    }
        }
        __syncthreads();
        #pragma unroll
        for (int i = 0; i < 8; i++) {
            int g = tid + 256 * i;
            int row = g >> 5, c4 = (g & 31) * 4;
            float4 v = *(float4*)&cf[row * 132 + c4];
            *(float4*)&Out[(size_t)(m0 + pass * 64 + row) * CC + n0 + c4] = v;
        }
    }
}

// ---------------------------------------------------------------------------
// LoRA stage-1, v3: 64x64 tiles (grid 256x6 = 1536 blocks, 2x occupancy).
// A staged by threads 0..127, B by threads 128..255 (parallel issue).
// Epilogue emits split-bf16 activations (K-padded).
// ---------------------------------------------------------------------------
__global__ __launch_bounds__(256) void lora1_all(
    const float* __restrict__ X,
    const float* __restrict__ w1, const float* __restrict__ a1,
    const float* __restrict__ v1, const float* __restrict__ g1,
    const float* __restrict__ xw, const float* __restrict__ xa,
    const float* __restrict__ xv, const float* __restrict__ xg,
    unsigned short* __restrict__ awh, unsigned short* __restrict__ awl,
    unsigned short* __restrict__ aah, unsigned short* __restrict__ aal,
    unsigned short* __restrict__ avh, unsigned short* __restrict__ avl,
    unsigned short* __restrict__ agh, unsigned short* __restrict__ agl)
{
    const int y = blockIdx.y;
    const float* W; const float* mix; unsigned short *Hi, *Lo;
    int Ncols, n0, epi, Kp;
    if (y == 0)      { W=w1; mix=xw; Hi=awh; Lo=awl; Ncols=64;  n0=0;          epi=1; Kp=64;  }
    else if (y == 1) { W=a1; mix=xa; Hi=aah; Lo=aal; Ncols=64;  n0=0;          epi=0; Kp=64;  }
    else if (y == 2) { W=v1; mix=xv; Hi=avh; Lo=avl; Ncols=32;  n0=0;          epi=0; Kp=64;  }
    else             { W=g1; mix=xg; Hi=agh; Lo=agl; Ncols=160; n0=(y-3)*64;   epi=2; Kp=192; }

    __shared__ float As[8][64];
    __shared__ float Bs[8][64];
    const int tid = threadIdx.x;
    const int m0 = blockIdx.x * 64;
    const int sr  = tid >> 1;          // A staging row 0..63 (tid<128)
    const int skq = (tid & 1) * 4;     // A staging k offset
    const int t2  = tid - 128;         // B staging thread (tid>=128)
    const int bkr = t2 >> 4;           // B k row 0..7
    const int bnq = (t2 & 15) * 4;     // B n offset
    const int tm = (tid >> 3) * 2;     // 32 row-groups x 2
    const int tn = (tid & 7) * 8;      // 8 col-groups x 8

    float acc[2][8];
    #pragma unroll
    for (int i = 0; i < 2; i++)
        #pragma unroll
        for (int j = 0; j < 8; j++) acc[i][j] = 0.f;

    auto ldAm = [&](int gm, int gk) -> float4 {
        const float* px = X + (size_t)gm * CC + gk;
        float4 xvv = *(const float4*)px;
        float4 pv;
        if ((gm & (TT - 1)) == 0) pv = make_float4(0.f, 0.f, 0.f, 0.f);
        else pv = *(const float4*)(px - CC);
        float4 mv = *(const float4*)(mix + gk);
        xvv.x += (pv.x - xvv.x) * mv.x;
        xvv.y += (pv.y - xvv.y) * mv.y;
        xvv.z += (pv.z - xvv.z) * mv.z;
        xvv.w += (pv.w - xvv.w) * mv.w;
        return xvv;
    };

    float4 aR = make_float4(0.f, 0.f, 0.f, 0.f);
    float4 bR = make_float4(0.f, 0.f, 0.f, 0.f);
    if (tid < 128) {
        aR = ldAm(m0 + sr, skq);
    } else {
        int gn = n0 + bnq;
        bR = (gn < Ncols) ? *(const float4*)(W + (size_t)bkr * Ncols + gn)
                          : make_float4(0.f, 0.f, 0.f, 0.f);
    }

    for (int k0 = 0; k0 < CC; k0 += 8) {
        __syncthreads();
        if (tid < 128) {
            As[skq + 0][sr] = aR.x;
            As[skq + 1][sr] = aR.y;
            As[skq + 2][sr] = aR.z;
            As[skq + 3][sr] = aR.w;
        } else {
            *(float4*)&Bs[bkr][bnq] = bR;
        }
        __syncthreads();

        if (k0 + 8 < CC) {
            if (tid < 128) {
                aR = ldAm(m0 + sr, k0 + 8 + skq);
            } else {
                int gn = n0 + bnq;
                bR = (gn < Ncols) ? *(const float4*)(W + (size_t)(k0 + 8 + bkr) * Ncols + gn)
                                  : make_float4(0.f, 0.f, 0.f, 0.f);
            }
        }

        #pragma unroll
        for (int kk = 0; kk < 8; ++kk) {
            float av[2], bv[8];
            av[0] = As[kk][tm];
            av[1] = As[kk][tm + 1];
            *(float4*)&bv[0] = *(const float4*)&Bs[kk][tn];
            *(float4*)&bv[4] = *(const float4*)&Bs[kk][tn + 4];
            #pragma unroll
            for (int i = 0; i < 2; i++)
                #pragma unroll
                for (int j = 0; j < 8; j++)
                    acc[i][j] = fmaf(av[i], bv[j], acc[i][j]);
        }
    }

    #pragma unroll
    for (int i = 0; i < 2; i++) {
        int gm = m0 + tm + i;
        int gn = n0 + tn;
        if (gn < Kp) {
            unsigned short h8[8], l8[8];
            #pragma unroll
            for (int j = 0; j < 8; j++) {
                float v = 0.f;
                if (gn + j < Ncols) {
                    v = acc[i][j];
                    if (epi == 1) v = tanhf(v);
                    else if (epi == 2) v = sigmoidf_(v);
                }
                h8[j] = f2bf(v);
                l8[j] = f2bf(v - bf2f(h8[j]));
            }
            uint4 H, L;
            H.x = (unsigned)h8[0] | ((unsigned)h8[1] << 16);
            H.y = (unsigned)h8[2] | ((unsigned)h8[3] << 16);
            H.z = (unsigned)h8[4] | ((unsigned)h8[5] << 16);
            H.w = (unsigned)h8[6] | ((unsigned)h8[7] << 16);
            L.x = (unsigned)l8[0] | ((unsigned)l8[1] << 16);
            L.y = (unsigned)l8[2] | ((unsigned)l8[3] << 16);
            L.z = (unsigned)l8[4] | ((unsigned)l8[5] << 16);
            L.w = (unsigned)l8[6] | ((unsigned)l8[7] << 16);
            *(uint4*)(Hi + (size_t)gm * Kp + gn) = H;
            *(uint4*)(Lo + (size_t)gm * Kp + gn) = L;
        }
    }
}

// ---------------------------------------------------------------------------
// LoRA stage-2 on MFMA (unchanged from round 12 — passed)
// ---------------------------------------------------------------------------
__global__ __launch_bounds__(256, 3) void lora2_mfma(
    const unsigned short* __restrict__ awh, const unsigned short* __restrict__ awl,
    const unsigned short* __restrict__ aah, const unsigned short* __restrict__ aal,
    const unsigned short* __restrict__ avh, const unsigned short* __restrict__ avl,
    const unsigned short* __restrict__ agh, const unsigned short* __restrict__ agl,
    const unsigned short* __restrict__ w2h, const unsigned short* __restrict__ w2l,
    const unsigned short* __restrict__ a2h, const unsigned short* __restrict__ a2l,
    const unsigned short* __restrict__ v2h, const unsigned short* __restrict__ v2l,
    const unsigned short* __restrict__ g2h, const unsigned short* __restrict__ g2l,
    const float* __restrict__ w0, const float* __restrict__ a0v,
    const float* __restrict__ v0v, const float* __restrict__ v_first,
    float* __restrict__ decb, float* __restrict__ ab,
    float* __restrict__ vbuf, float* __restrict__ gb)
{
    __shared__ __align__(16) unsigned short lds[24576];   // 48 KB
    const int z = blockIdx.z;
    const unsigned short *Ah, *Al, *Bh, *Bl; int Kp;
    if (z == 0)      { Ah = awh; Al = awl; Bh = w2h; Bl = w2l; Kp = 64;  }
    else if (z == 1) { Ah = aah; Al = aal; Bh = a2h; Bl = a2l; Kp = 64;  }
    else if (z == 2) { Ah = avh; Al = avl; Bh = v2h; Bl = v2l; Kp = 64;  }
    else             { Ah = agh; Al = agl; Bh = g2h; Bl = g2l; Kp = 192; }

    const int tid = threadIdx.x, lane = tid & 63, wave = tid >> 6;
    const int wm = (wave >> 1) * 64, wn = (wave & 1) * 32;
    const int m0 = blockIdx.x * 128, n0 = blockIdx.y * 64;

    f32x4 acc[4][2];
    #pragma unroll
    for (int i = 0; i < 4; i++)
        #pragma unroll
        for (int jj = 0; jj < 2; jj++)
            acc[i][jj] = (f32x4){0.f, 0.f, 0.f, 0.f};

    for (int k0 = 0; k0 < Kp; k0 += 64) {
        #pragma unroll
        for (int p = 0; p < 2; p++) {
            const unsigned short* sbase = (p == 0) ? Ah : Al;
            #pragma unroll
            for (int i = 0; i < 4; i++) {
                int slot = i * 256 + wave * 64 + lane;
                int row = slot >> 3, gsl = slot & 7;
                const unsigned short* src = sbase
                    + (size_t)(m0 + row) * Kp + k0 + ((gsl ^ (row & 7)) * 8);
                gll16(src, &lds[(size_t)(p * 8192) + (size_t)(i * 256 + wave * 64) * 8]);
            }
        }
        #pragma unroll
        for (int p = 0; p < 2; p++) {
            const unsigned short* sbase = (p == 0) ? Bh : Bl;
            #pragma unroll
            for (int i = 0; i < 2; i++) {
                int slot = i * 256 + wave * 64 + lane;
                int row = slot >> 3, gsl = slot & 7;
                const unsigned short* src = sbase
                    + (size_t)(n0 + row) * Kp + k0 + ((gsl ^ (row & 7)) * 8);
                gll16(src, &lds[(size_t)(16384 + p * 4096) + (size_t)(i * 256 + wave * 64) * 8]);
            }
        }
        __syncthreads();

        #pragma unroll
        for (int ks = 0; ks < 2; ks++) {
            bf16x8 bhf[2], blf[2];
            #pragma unroll
            for (int nt = 0; nt < 2; nt++) {
                int col = wn + nt * 16 + (lane & 15);
                int gk = ks * 4 + (lane >> 4);
                int el = col * 64 + ((gk ^ (col & 7)) * 8);
                bhf[nt] = *(const bf16x8*)&lds[16384 + el];
                blf[nt] = *(const bf16x8*)&lds[20480 + el];
            }
            #pragma unroll
            for (int mt = 0; mt < 4; mt++) {
                int row = wm + mt * 16 + (lane & 15);
                int gk = ks * 4 + (lane >> 4);
                int el = row * 64 + ((gk ^ (row & 7)) * 8);
                bf16x8 ahf = *(const bf16x8*)&lds[el];
                bf16x8 alf = *(const bf16x8*)&lds[8192 + el];
                #pragma unroll
                for (int nt = 0; nt < 2; nt++) {
                    acc[mt][nt] = __builtin_amdgcn_mfma_f32_16x16x32_bf16(
                        ahf, bhf[nt], acc[mt][nt], 0, 0, 0);
                    acc[mt][nt] = __builtin_amdgcn_mfma_f32_16x16x32_bf16(
                        alf, bhf[nt], acc[mt][nt], 0, 0, 0);
                    acc[mt][nt] = __builtin_amdgcn_mfma_f32_16x16x32_bf16(
                        ahf, blf[nt], acc[mt][nt], 0, 0, 0);
                }
            }
        }
        __syncthreads();
    }
    float* cf = (float*)&lds[0];
    #pragma unroll
    for (int mt = 0; mt < 4; mt++)
        #pragma unroll
        for (int nt = 0; nt < 2; nt++)
            #pragma unroll
            for (int r = 0; r < 4; r++) {
                int row = wm + mt * 16 + (lane >> 4) * 4 + r;
                int col = wn + nt * 16 + (lane & 15);
                cf[row * 68 + col] = acc[mt][nt][r];
            }
    __syncthreads();
    #pragma unroll
    for (int i = 0; i < 8; i++) {
        int idx = tid + 256 * i;
        int row = idx >> 4, c4 = (idx & 15) * 4;
        float4 v = *(float4*)&cf[row * 68 + c4];
        int gm = m0 + row;
        int c = n0 + c4;
        size_t off = (size_t)gm * CC + c;
        if (z == 0) {
            float4 w0q = *(const float4*)(w0 + c);
            float4 o;
            o.x = expf(-expf(-log1pf(expf(-(w0q.x + v.x))) - 0.5f));
            o.y = expf(-expf(-log1pf(expf(-(w0q.y + v.y))) - 0.5f));
            o.z = expf(-expf(-log1pf(expf(-(w0q.z + v.z))) - 0.5f));
            o.w = expf(-expf(-log1pf(expf(-(w0q.w + v.w))) - 0.5f));
            *(float4*)&decb[off] = o;
        } else if (z == 1) {
            float4 a0q = *(const float4*)(a0v + c);
            float4 o;
            o.x = sigmoidf_(a0q.x + v.x);
            o.y = sigmoidf_(a0q.y + v.y);
            o.z = sigmoidf_(a0q.z + v.z);
            o.w = sigmoidf_(a0q.w + v.w);
            *(float4*)&ab[off] = o;
        } else if (z == 2) {
            float4 v0q = *(const float4*)(v0v + c);
            float4 vr = *(const float4*)&vbuf[off];
            float4 vf = *(const float4*)&v_first[off];
            float4 o;
            o.x = vr.x + (vf.x - vr.x) * sigmoidf_(v0q.x + v.x);
            o.y = vr.y + (vf.y - vr.y) * sigmoidf_(v0q.y + v.y);
            o.z = vr.z + (vf.z - vr.z) * sigmoidf_(v0q.z + v.z);
            o.w = vr.w + (vf.w - vr.w) * sigmoidf_(v0q.w + v.w);
            *(float4*)&vbuf[off] = o;
        } else {
            *(float4*)&gb[off] = v;
        }
    }
}

// ---------------------------------------------------------------------------
// Chunked WKV phases A, B, C (unchanged — passed)
// ---------------------------------------------------------------------------
__global__ __launch_bounds__(256) void wkvA(
    const float* __restrict__ kb, const float* __restrict__ ab,
    const float* __restrict__ vb, const float* __restrict__ decb,
    const float* __restrict__ k_k, const float* __restrict__ k_a,
    float* __restrict__ Gb, float* __restrict__ Ub,
    float* __restrict__ Bpb, float* __restrict__ Kpb,
    float* __restrict__ wcb, int cb)
{
    __shared__ __align__(16) float sAp[64 * STR];
    __shared__ __align__(16) float sBp[64 * STR];
    __shared__ __align__(16) float sKp[64 * STR];
    __shared__ __align__(16) float sT [64 * STR];
    __shared__ float sSeg[4][64];
    const int inst = blockIdx.x;
    const int bhd = inst >> 3, lc = inst & 7;
    const int dir = bhd & 1, bh = bhd >> 1, b = bh >> 4, h = bh & 15;
    const int c64 = (cb * CB + lc) * LCH;
    const int tid = threadIdx.x;
    const int lane = tid & 63, seg = tid >> 6;
    const int ch = h * 64 + lane;
    const size_t gbase = (size_t)inst * 4096;

    float loc[16];
    {
        float run = 1.f;
        #pragma unroll
        for (int i = 0; i < 16; i++) {
            int p = seg * 16 + i;
            int t = dir ? (TMAX - (c64 + p)) : (c64 + p);
            float d = decb[((size_t)(b * TT + t)) * CC + ch];
            run *= d; loc[i] = run;
        }
        sSeg[seg][lane] = run;
    }
    __syncthreads();
    float pre = 1.f;
    for (int s2 = 0; s2 < seg; ++s2) pre *= sSeg[s2][lane];
    {
        const float kkl = k_k[ch], kal = k_a[ch];
        #pragma unroll
        for (int i = 0; i < 16; i++) {
            int p = seg * 16 + i;
            int t = dir ? (TMAX - (c64 + p)) : (c64 + p);
            size_t ra = ((size_t)(b * TT + t)) * CC + ch;
            float kraw = kb[ra], asig = ab[ra];
            float kkv = kraw * kkl;
            float s2 = waveReduceSum(kkv * kkv);
            float kkn = kkv / fmaxf(sqrtf(s2), 1e-12f);
            float wc = loc[i] * pre;
            float wx = (i == 0) ? pre : loc[i - 1] * pre;
            float apv = -kkn * wx;
            float bpv = kkn * asig / wc;
            float kpv = kraw * (1.f + (asig - 1.f) * kal) / wc;
            sAp[lane * STR + p] = apv;
            sBp[lane * STR + p] = bpv;
            sKp[lane * STR + p] = kpv;
            Bpb[gbase + p * 64 + lane] = bpv;
            Kpb[gbase + p * 64 + lane] = kpv;
            wcb[gbase + p * 64 + lane] = wc;
        }
    }
    __syncthreads();

    const int tr = (tid >> 4) * 4, tc = (tid & 15) * 4;
    {
        float acc[4][4] = {};
        gemm64<1, STR, 1, STR>(sAp, sKp, acc, tr, tc);
        #pragma unroll
        for (int r = 0; r < 4; r++)
            #pragma unroll
            for (int cq = 0; cq < 4; cq++)
                sT[(tr + r) * STR + tc + cq] = (tc + cq < tr + r) ? acc[r][cq] : 0.f;
    }
    __syncthreads();
    {
        float accY[4][4] = {};
        const float* vbase = vb + ((size_t)(b * TT + (dir ? (TMAX - c64) : c64))) * CC
                           + h * 64 + tc;
        const ptrdiff_t vstep = dir ? -(ptrdiff_t)CC : (ptrdiff_t)CC;
        #pragma unroll 2
        for (int j4 = 0; j4 < 64; j4 += 4) {
            float a_[4][4];
            #pragma unroll
            for (int r = 0; r < 4; r++) {
                float4 t4 = *(const float4*)&sT[(tr + r) * STR + j4];
                a_[r][0] = t4.x; a_[r][1] = t4.y; a_[r][2] = t4.z; a_[r][3] = t4.w;
            }
            float4 vq[4];
            #pragma unroll
            for (int kk = 0; kk < 4; kk++)
                vq[kk] = *(const float4*)(vbase + (ptrdiff_t)(j4 + kk) * vstep);
            #pragma unroll
            for (int r = 0; r < 4; r++) {
                accY[r][0] = fmaf(a_[r][0], vq[0].x, fmaf(a_[r][1], vq[1].x,
                             fmaf(a_[r][2], vq[2].x, fmaf(a_[r][3], vq[3].x, accY[r][0]))));
                accY[r][1] = fmaf(a_[r][0], vq[0].y, fmaf(a_[r][1], vq[1].y,
                             fmaf(a_[r][2], vq[2].y, fmaf(a_[r][3], vq[3].y, accY[r][1]))));
                accY[r][2] = fmaf(a_[r][0], vq[0].z, fmaf(a_[r][1], vq[1].z,
                             fmaf(a_[r][2], vq[2].z, fmaf(a_[r][3], vq[3].z, accY[r][2]))));
                accY[r][3] = fmaf(a_[r][0], vq[0].w, fmaf(a_[r][1], vq[1].w,
                             fmaf(a_[r][2], vq[2].w, fmaf(a_[r][3], vq[3].w, accY[r][3]))));
            }
        }
        #pragma unroll
        for (int r = 0; r < 4; r++)
            #pragma unroll
            for (int cq = 0; cq < 4; cq++)
                sKp[(tr + r) * STR + tc + cq] = accY[r][cq];
    }
    __syncthreads();
    {
        float acc[4][4] = {};
        gemm64<1, STR, 1, STR>(sAp, sBp, acc, tr, tc);
        #pragma unroll
        for (int r = 0; r < 4; r++)
            #pragma unroll
            for (int cq = 0; cq < 4; cq++)
                sT[(tr + r) * STR + tc + cq] = (tc + cq < tr + r) ? acc[r][cq] : 0.f;
    }
    __syncthreads();
    if (tid < 64) {
        for (int r = 0; r < 64; ++r) {
            float acc = 0.f;
            for (int s = 0; s < r; ++s)
                acc = fmaf(sT[r * STR + s], sBp[s * STR + tid], acc);
            sBp[r * STR + tid] = (r == tid) ? 1.f : acc;
        }
    }
    __syncthreads();
    {
        float accG[4][4] = {};
        gemm64<STR, 1, STR, 1>(sBp, sAp, accG, tr, tc);
        float accU[4][4] = {};
        gemm64<STR, 1, 1, STR>(sBp, sKp, accU, tr, tc);
        #pragma unroll
        for (int r = 0; r < 4; r++) {
            *(float4*)&Gb[gbase + (tr + r) * 64 + tc] =
                make_float4(accG[r][0], accG[r][1], accG[r][2], accG[r][3]);
            *(float4*)&Ub[gbase + (tr + r) * 64 + tc] =
                make_float4(accU[r][0], accU[r][1], accU[r][2], accU[r][3]);
        }
    }
}

__global__ __launch_bounds__(256) void wkvB(
    const float* __restrict__ vb,
    const float* __restrict__ Gb, float* __restrict__ Ub,
    const float* __restrict__ Bpb, const float* __restrict__ Kpb,
    const float* __restrict__ wcb, float* __restrict__ S0b,
    float* __restrict__ Scur, int cb)
{
    __shared__ __align__(16) float sS[64 * STR];
    __shared__ __align__(16) float sG[64 * STR];
    __shared__ __align__(16) float sU[64 * STR];
    __shared__ __align__(16) float sB[64 * STR];
    __shared__ __align__(16) float sK[64 * STR];
    __shared__ __align__(16) float sV[64 * STR];
    const int bhd = blockIdx.x;
    const int dir = bhd & 1, bh = bhd >> 1, b = bh >> 4, h = bh & 15;
    const int tid = threadIdx.x;
    const int tr = (tid >> 4) * 4, tc = (tid & 15) * 4;

    for (int i = tid; i < 4096; i += 256)
        sS[(i >> 6) * STR + (i & 63)] = Scur[(size_t)bhd * 4096 + i];
    __syncthreads();

    for (int lc = 0; lc < CB; ++lc) {
        const int inst = bhd * CB + lc;
        const size_t gbase = (size_t)inst * 4096;
        const int c64 = (cb * CB + lc) * LCH;
        for (int i = tid; i < 4096; i += 256) {
            int rr = i >> 6, jj = i & 63;
            sG[rr * STR + jj] = Gb[gbase + i];
            sB[rr * STR + jj] = Bpb[gbase + i];
            sK[rr * STR + jj] = Kpb[gbase + i];
            int t = dir ? (TMAX - (c64 + rr)) : (c64 + rr);
            sV[rr * STR + jj] = vb[((size_t)(b * TT + t)) * CC + h * 64 + jj];
            S0b[gbase + i] = sS[rr * STR + jj];
        }
        __syncthreads();
        {
            float acc[4][4];
            #pragma unroll
            for (int r = 0; r < 4; r++) {
                float4 u0 = *(const float4*)&Ub[gbase + (tr + r) * 64 + tc];
                acc[r][0] = u0.x; acc[r][1] = u0.y; acc[r][2] = u0.z; acc[r][3] = u0.w;
            }
            gemm64<STR, 1, STR, 1>(sG, sS, acc, tr, tc);
            #pragma unroll
            for (int r = 0; r < 4; r++) {
                #pragma unroll
                for (int cq = 0; cq < 4; cq++) sU[(tr + r) * STR + tc + cq] = acc[r][cq];
                *(float4*)&Ub[gbase + (tr + r) * 64 + tc] =
                    make_float4(acc[r][0], acc[r][1], acc[r][2], acc[r][3]);
            }
        }
        __syncthreads();
        {
            float acc[4][4] = {};
            gemm64<1, STR, 1, STR>(sU, sB, acc, tr, tc);
            gemm64<1, STR, 1, STR>(sV, sK, acc, tr, tc);
            float w63[4];
            #pragma unroll
            for (int cq = 0; cq < 4; cq++) w63[cq] = wcb[gbase + 63 * 64 + tc + cq];
            #pragma unroll
            for (int r = 0; r < 4; r++)
                #pragma unroll
                for (int cq = 0; cq < 4; cq++) {
                    float sv = sS[(tr + r) * STR + tc + cq];
                    acc[r][cq] = (sv + acc[r][cq]) * w63[cq];
                }
            #pragma unroll
            for (int r = 0; r < 4; r++)
                #pragma unroll
                for (int cq = 0; cq < 4; cq++)
                    sS[(tr + r) * STR + tc + cq] = acc[r][cq];
        }
        __syncthreads();
    }
    for (int i = tid; i < 4096; i += 256)
        Scur[(size_t)bhd * 4096 + i] = sS[(i >> 6) * STR + (i & 63)];
}

__global__ __launch_bounds__(256) void wkvC(
    const float* __restrict__ rb, const float* __restrict__ vb,
    const float* __restrict__ Bpb, const float* __restrict__ Kpb,
    const float* __restrict__ Ub, const float* __restrict__ S0b,
    const float* __restrict__ wcb, const float* __restrict__ alpha_p,
    float* __restrict__ yb, int cb)
{
    __shared__ __align__(16) float sR[64 * STR];
    __shared__ __align__(16) float sO[64 * STR];
    __shared__ __align__(16) float sT2[64 * STR];
    const int inst = blockIdx.x;
    const int bhd = inst >> 3, lc = inst & 7;
    const int dir = bhd & 1, bh = bhd >> 1, b = bh >> 4, h = bh & 15;
    const int c64 = (cb * CB + lc) * LCH;
    const int tid = threadIdx.x, lane = tid & 63, seg = tid >> 6;
    const size_t gbase = (size_t)inst * 4096;
    const float alpha = alpha_p[0];
    const float wscale = dir ? (1.f - alpha) : alpha;
    const bool first = (cb < NB / 2);

    #pragma unroll
    for (int i = 0; i < 16; i++) {
        int p = seg * 16 + i;
        int t = dir ? (TMAX - (c64 + p)) : (c64 + p);
        size_t ra = ((size_t)(b * TT + t)) * CC + h * 64 + lane;
        float wc = wcb[gbase + p * 64 + lane];
        sR[lane * STR + p] = rb[ra] * wc;
        sO[lane * STR + p] = Bpb[gbase + p * 64 + lane];
    }
    __syncthreads();
    const int tr = (tid >> 4) * 4, tc = (tid & 15) * 4;
    float accO[4][4] = {};
    {
        float acc[4][4] = {};
        gemm64<1, STR, 1, STR>(sR, sO, acc, tr, tc);
        #pragma unroll
        for (int r = 0; r < 4; r++)
            #pragma unroll
            for (int cq = 0; cq < 4; cq++)
                sT2[(tr + r) * STR + tc + cq] = (tc + cq <= tr + r) ? acc[r][cq] : 0.f;
    }
    __syncthreads();
    for (int i = tid; i < 4096; i += 256)
        sO[(i >> 6) * STR + (i & 63)] = Ub[gbase + i];
    __syncthreads();
    gemm64<STR, 1, 1, STR>(sT2, sO, accO, tr, tc);
    __syncthreads();
    #pragma unroll
    for (int i = 0; i < 16; i++) {
        int p = seg * 16 + i;
        sO[lane * STR + p] = Kpb[gbase + p * 64 + lane];
    }
    __syncthreads();
    {
        float acc[4][4] = {};
        gemm64<1, STR, 1, STR>(sR, sO, acc, tr, tc);
        #pragma unroll
        for (int r = 0; r < 4; r++)
            #pragma unroll
            for (int cq = 0; cq < 4; cq++)
                sT2[(tr + r) * STR + tc + cq] = (tc + cq <= tr + r) ? acc[r][cq] : 0.f;
    }
    __syncthreads();
    #pragma unroll
    for (int i = 0; i < 16; i++) {
        int p = seg * 16 + i;
        int t = dir ? (TMAX - (c64 + p)) : (c64 + p);
        sO[p * STR + lane] = vb[((size_t)(b * TT + t)) * CC + h * 64 + lane];
    }
    __syncthreads();
    gemm64<STR, 1, 1, STR>(sT2, sO, accO, tr, tc);
    __syncthreads();
    for (int i = tid; i < 4096; i += 256)
        sO[(i >> 6) * STR + (i & 63)] = S0b[gbase + i];
    __syncthreads();
    gemm64<1, STR, STR, 1>(sR, sO, accO, tr, tc);
    #pragma unroll
    for (int r = 0; r < 4; r++) {
        int p = tr + r;
        int t = dir ? (TMAX - (c64 + p)) : (c64 + p);
        float* yp = &yb[((size_t)(b * TT + t)) * CC + h * 64 + tc];
        float4 o;
        if (first) {
            o.x = wscale * accO[r][0];
            o.y = wscale * accO[r][1];
            o.z = wscale * accO[r][2];
            o.w = wscale * accO[r][3];
        } else {
            float4 old = *(float4*)yp;
            o.x = old.x + wscale * accO[r][0];
            o.y = old.y + wscale * accO[r][1];
            o.z = old.z + wscale * accO[r][2];
            o.w = old.w + wscale * accO[r][3];
        }
        *(float4*)yp = o;
    }
}

// ---------------------------------------------------------------------------
// Post: GroupNorm + affine + bonus + gating; emits z as split bf16 (hi+lo).
// ---------------------------------------------------------------------------
__global__ __launch_bounds__(256) void post_kernel(
    const float* __restrict__ yb, const float* __restrict__ rbv,
    const float* __restrict__ kbv, const float* __restrict__ abv,
    const float* __restrict__ vbv, const float* __restrict__ gbv,
    const float* __restrict__ kaw, const float* __restrict__ r_k,
    const float* __restrict__ ln_w, const float* __restrict__ ln_b,
    unsigned short* __restrict__ zh, unsigned short* __restrict__ zl)
{
    const int t = blockIdx.x;
    const int tid = threadIdx.x;
    const size_t base = (size_t)t * CC;
    #pragma unroll
    for (int j = 0; j < 4; j++) {
        int c = tid + 256 * j;
        float y = yb[base + c];
        float s1 = waveReduceSum(y);
        float s2 = waveReduceSum(y * y);
        float mu = s1 * (1.0f / 64.0f);
        float var = s2 * (1.0f / 64.0f) - mu * mu;
        float yn = (y - mu) * rsqrtf(var + EPS_GN);
        yn = yn * ln_w[c] + ln_b[c];
        float rv = rbv[base + c];
        float kf = kbv[base + c] * (1.0f + (abv[base + c] - 1.0f) * kaw[c]);
        float vv = vbv[base + c];
        float dot = waveReduceSum(rv * kf * r_k[c]);
        yn += dot * vv;
        float z = yn * gbv[base + c];
        unsigned short h = f2bf(z);
        zh[base + c] = h;
        zl[base + c] = f2bf(z - bf2f(h));
    }
}

// ---------------------------------------------------------------------------
extern "C" void kernel_launch(void* const* d_in, const int* in_sizes, int n_in,
                              void* d_out, int out_size, void* d_ws, size_t ws_size,
                              hipStream_t stream)
{
    (void)in_sizes; (void)n_in; (void)out_size; (void)ws_size;
    const float* x      = (const float*)d_in[0];
    const float* vfirst = (const float*)d_in[1];
    const float* x_r    = (const float*)d_in[2];
    const float* x_w    = (const float*)d_in[3];
    const float* x_k    = (const float*)d_in[4];
    const float* x_v    = (const float*)d_in[5];
    const float* x_a    = (const float*)d_in[6];
    const float* x_g    = (const float*)d_in[7];
    const float* w0     = (const float*)d_in[8];
    const float* w1     = (const float*)d_in[9];
    const float* w2     = (const float*)d_in[10];
    const float* a0     = (const float*)d_in[11];
    const float* a1     = (const float*)d_in[12];
    const float* a2     = (const float*)d_in[13];
    const float* v0     = (const float*)d_in[14];
    const float* v1     = (const float*)d_in[15];
    const float* v2     = (const float*)d_in[16];
    const float* g1     = (const float*)d_in[17];
    const float* g2     = (const float*)d_in[18];
    const float* k_k    = (const float*)d_in[19];
    const float* k_a    = (const float*)d_in[20];
    const float* r_k    = (const float*)d_in[21];
    const float* Wr     = (const float*)d_in[22];
    const float* Wk     = (const float*)d_in[23];
    const float* Wv     = (const float*)d_in[24];
    const float* Wo     = (const float*)d_in[25];
    const float* ln_w   = (const float*)d_in[26];
    const float* ln_b   = (const float*)d_in[27];
    const float* alpha  = (const float*)d_in[28];

    const size_t SZ = (size_t)BT * CC;
    const size_t CHB = (size_t)1024 * 4096;
    float* ws   = (float*)d_ws;
    float* rb   = ws + 0 * SZ;
    float* kb   = ws + 1 * SZ;
    float* vb   = ws + 2 * SZ;
    float* decb = ws + 3 * SZ;
    float* ab   = ws + 4 * SZ;
    float* actf = ws + 5 * SZ;
    unsigned short* awh = (unsigned short*)actf;
    unsigned short* awl = awh + (size_t)BT * 64;
    unsigned short* aah = awl + (size_t)BT * 64;
    unsigned short* aal = aah + (size_t)BT * 64;
    unsigned short* avh = aal + (size_t)BT * 64;
    unsigned short* avl = avh + (size_t)BT * 64;
    unsigned short* agh = avl + (size_t)BT * 64;
    unsigned short* agl = agh + (size_t)BT * 192;
    float* Gb   = actf + (size_t)BT * 384;
    float* Ub   = Gb + CHB;
    float* Bpb  = Ub + CHB;
    float* Kpb  = Bpb + CHB;
    float* S0b  = Kpb + CHB;
    float* wcb  = S0b + CHB;
    float* Scur = wcb + CHB;
    unsigned short* Whb = (unsigned short*)(Scur + (size_t)128 * 4096);
    unsigned short* Wlb = Whb + (size_t)CC * CC;
    unsigned short* w2th = Wlb + (size_t)CC * CC;
    unsigned short* w2tl = w2th + (size_t)CC * 64;
    unsigned short* a2th = w2tl + (size_t)CC * 64;
    unsigned short* a2tl = a2th + (size_t)CC * 64;
    unsigned short* v2th = a2tl + (size_t)CC * 64;
    unsigned short* v2tl = v2th + (size_t)CC * 64;
    unsigned short* g2th = v2tl + (size_t)CC * 64;
    unsigned short* g2tl = g2th + (size_t)CC * 192;
    float* outp = (float*)d_out;
    unsigned short* xrh = (unsigned short*)outp;          // [0, SZ)
    unsigned short* xrl = xrh + SZ;                       // [SZ, 2SZ)
    unsigned short* xkh = xrl + SZ;                       // [2SZ, 3SZ)
    unsigned short* xkl = xkh + SZ;                       // [3SZ, 4SZ)
    unsigned short* xvh = (unsigned short*)decb;
    unsigned short* xvl = xvh + SZ;
    float* gb   = outp;
    float* yb   = outp + SZ;
    unsigned short* zAh = (unsigned short*)decb;
    unsigned short* zAl = zAh + SZ;

    dim3 blk(256);
    const int NG_A = BT * (CC / 8);
    const int NG_W = CC * (CC / 8);
    dim3 gridA(NG_A / 256), gridW(NG_W / 256);
    dim3 gridG(1024);

    // fused x-mix split (xr, xk, xv) — reads x once
    conv_split_x3<<<gridA, blk, 0, stream>>>(x, x_r, x_k, x_v,
                                             xrh, xrl, xkh, xkl, xvh, xvl);
    // big projections
    conv_split<false><<<gridW, blk, 0, stream>>>(Wr, nullptr, Whb, Wlb, NG_W);
    gemm_split_bf16<<<gridG, blk, 0, stream>>>(xrh, xrl, Whb, Wlb, rb);
    conv_split<false><<<gridW, blk, 0, stream>>>(Wk, nullptr, Whb, Wlb, NG_W);
    gemm_split_bf16<<<gridG, blk, 0, stream>>>(xkh, xkl, Whb, Wlb, kb);
    conv_split<false><<<gridW, blk, 0, stream>>>(Wv, nullptr, Whb, Wlb, NG_W);
    gemm_split_bf16<<<gridG, blk, 0, stream>>>(xvh, xvl, Whb, Wlb, vb);

    // stage-2 weight conversion (transpose + split + K-pad)
    conv_w2<<<dim3(32), blk, 0, stream>>>(w2, 64, 64, w2th, w2tl);
    conv_w2<<<dim3(32), blk, 0, stream>>>(a2, 64, 64, a2th, a2tl);
    conv_w2<<<dim3(32), blk, 0, stream>>>(v2, 32, 64, v2th, v2tl);
    conv_w2<<<dim3(96), blk, 0, stream>>>(g2, 160, 192, g2th, g2tl);

    // LoRA stage-1 (64x64 tiles, 1536 blocks) then stage-2 on MFMA
    lora1_all<<<dim3(BT / 64, 6), blk, 0, stream>>>(x, w1, a1, v1, g1,
        x_w, x_a, x_v, x_g, awh, awl, aah, aal, avh, avl, agh, agl);
    lora2_mfma<<<dim3(BT / 128, CC / 64, 4), blk, 0, stream>>>(
        awh, awl, aah, aal, avh, avl, agh, agl,
        w2th, w2tl, a2th, a2tl, v2th, v2tl, g2th, g2tl,
        w0, a0, v0, vfirst, decb, ab, vb, gb);

    // chunked bidirectional WKV
    hipMemsetAsync(Scur, 0, (size_t)128 * 4096 * sizeof(float), stream);
    for (int cb = 0; cb < NB; ++cb) {
        wkvA<<<dim3(1024), blk, 0, stream>>>(kb, ab, vb, decb, k_k, k_a,
                                             Gb, Ub, Bpb, Kpb, wcb, cb);
        wkvB<<<dim3(128), blk, 0, stream>>>(vb, Gb, Ub, Bpb, Kpb, wcb, S0b, Scur, cb);
        wkvC<<<dim3(1024), blk, 0, stream>>>(rb, vb, Bpb, Kpb, Ub, S0b, wcb,
                                             alpha, yb, cb);
    }

    // groupnorm + bonus + gate -> split bf16 z (into decb's slot)
    post_kernel<<<dim3(BT), blk, 0, stream>>>(yb, rb, kb, ab, vb, gb, k_a, r_k,
                                              ln_w, ln_b, zAh, zAl);
    // final projection
    conv_split<false><<<gridW, blk, 0, stream>>>(Wo, nullptr, Whb, Wlb, NG_W);
    hipMemcpyAsync(outp + SZ, vfirst, SZ * sizeof(float),
                   hipMemcpyDeviceToDevice, stream);
    gemm_split_bf16<<<gridG, blk, 0, stream>>>(zAh, zAl, Whb, Wlb, outp);
}